// Round 9
// baseline (57.607 us; speedup 1.0000x reference)
//
#include <hip/hip_runtime.h>
#include <cstdint>
#include <cstddef>

#define NB 128      // N
#define KPP 32      // Kp
#define VV 2048     // V
#define SS 200      // S (tm1)
#define WID 32      // width == K
#define NEXT_BASE (KPP*VV)     // 65536
#define ROWS_PB 2              // k-rows per block (2 waves per row)
#define KBLK 16                // blocks per n
#define CAPW 128               // per-wave survivor cap
#define BCAP (4*CAPW)          // block survivor cap (512)
#define NLIST (KBLK*WID + WID) // 544 merge candidates

// output layout (flat f32, concat in return order)
#define SZ_YNEXT ((size_t)(SS+1)*NB*WID)               // 823296
#define NK       ((size_t)NB*WID)                      // 4096
#define O_LAST   (SZ_YNEXT)
#define O_LENS   (SZ_YNEXT + NK)
#define O_NB     (SZ_YNEXT + 2*NK)
#define O_B      (SZ_YNEXT + 3*NK)
#define O_PREF   (SZ_YNEXT + 4*NK)                     // size NB*WID*WID
#define O_SRC    (SZ_YNEXT + 4*NK + (size_t)NB*WID*WID)
#define O_NOEXT  (SZ_YNEXT + 5*NK + (size_t)NB*WID*WID)

__device__ __forceinline__ unsigned fkey(float f) {
    unsigned u = __float_as_uint(f);
    return (u & 0x80000000u) ? ~u : (u | 0x80000000u);
}
__device__ __forceinline__ float funkey(unsigned k) {
    unsigned u = (k & 0x80000000u) ? (k & 0x7FFFFFFFu) : ~k;
    return __uint_as_float(u);
}
__device__ __forceinline__ unsigned long long shflx64(unsigned long long v, int m) {
    int lo = __shfl_xor((int)(unsigned)v, m);
    int hi = __shfl_xor((int)(unsigned)(v >> 32), m);
    return ((unsigned long long)(unsigned)hi << 32) | (unsigned)lo;
}

// ---------------- kernel A: one wave per HALF k-row; ballot-radix tau; block list ----------------
__global__ __launch_bounds__(256) void slice_topk_kernel(
    const float* __restrict__ ext,     // [N][Kp][V]
    const float* __restrict__ nbp_g,   // [N][Kp]
    const float* __restrict__ bp_g,    // [N][Kp]
    const int*   __restrict__ yprev,   // [S][N][Kp]
    const int*   __restrict__ ylast,   // [N][Kp]
    const int*   __restrict__ ylens,   // [N][Kp]
    const int*   __restrict__ pip,     // [N][Kp][Kp]
    unsigned* __restrict__ wsF, int* __restrict__ wsI, float* __restrict__ wsAb)
{
    const int blk  = blockIdx.x;
    const int n    = blk >> 4;          // KBLK = 16
    const int kb   = blk & 15;
    const int tid  = threadIdx.x;
    const int w    = tid >> 6;          // 4 waves
    const int lane = tid & 63;
    const int k    = kb*ROWS_PB + (w >> 1);
    const int half = w & 1;

    __shared__ unsigned s_hm[4][VV/32];     // per-wave private hm (full row), 1 KB
    __shared__ unsigned s_lf[BCAP];         // block survivor list
    __shared__ int      s_li[BCAP];
    __shared__ int      s_cnt;

    if (tid == 0) s_cnt = 0;
    s_hm[w][lane] = 0u;
    __syncthreads();                        // s_cnt/s_hm init visible before use

    // per-row params (wave-uniform addresses -> broadcast loads)
    const int   tlen = ylens[n*KPP + k];
    int last = ylast[n*KPP + k]; last = min(max(last, 0), VV-1);
    const float nbp = nbp_g[n*KPP + k];
    const float bp  = bp_g[n*KPP + k];

    // issue the 4 float4 loads early (16 floats/lane, registers only)
    const float4* g4 = (const float4*)(ext + ((size_t)n*KPP + k)*VV + half*1024);
    float4 f[4];
    #pragma unroll
    for (int j = 0; j < 4; ++j) f[j] = g4[lane + 64*j];

    // has-match bits + absorb terms for this k-row
    if (lane < KPP) {
        int j = lane;
        int tcl = min(max(tlen, 0), SS-1);
        int tm  = yprev[((size_t)tcl*NB + n)*KPP + j];
        tm = min(max(tm, 0), VV-1);
        bool ex = (tlen + 1 == ylens[n*KPP + j]) && (pip[((size_t)n*KPP + k)*KPP + j] != 0);
        if (ex) atomicOr(&s_hm[w][tm >> 5], 1u << (tm & 31));
        if (half == 0) {   // absorb term for (k, j): uses UNMASKED candidate value
            float ev = ex ? ext[((size_t)n*KPP + k)*VV + tm] : 0.0f;
            float bb = (tm == last) ? 0.0f : nbp;
            wsAb[((size_t)n*KPP + k)*KPP + j] = ex ? (bb + bp)*ev : 0.0f;
        }
    }

    // 16 keys in registers; v_local = 4*lane + 256*j + e in [0,1024)
    unsigned key[16];
    #pragma unroll
    for (int j = 0; j < 4; ++j) {
        const float fe[4] = {f[j].x, f[j].y, f[j].z, f[j].w};
        #pragma unroll
        for (int e = 0; e < 4; ++e) {
            int vl = 4*lane + 256*j + e;
            int v  = (half << 10) + vl;
            float base = (v == last) ? 0.0f : nbp;
            float val  = (base + bp) * fe[e];
            if ((s_hm[w][v >> 5] >> (v & 31)) & 1u) val = -INFINITY;
            key[j*4 + e] = fkey(val);
        }
    }

    // lane max
    unsigned m = key[0];
    #pragma unroll
    for (int i = 1; i < 16; ++i) m = max(m, key[i]);

    // tau = EXACT 32nd-largest of the 64 lane maxima, via ballot radix (no LDS chain)
    unsigned tau = 0;
    {
        int need = 32;
        #pragma unroll
        for (int b = 31; b >= 0; --b) {
            unsigned pb1 = (tau >> b) | 1u;
            unsigned long long msk = __ballot((m >> b) == pb1);
            int cnt = __popcll(msk);
            if (cnt >= need) tau |= (1u << b);
            else             need -= cnt;
        }
    }
    // guarantee: >=32 lanes have m >= tau  =>  >=32 keys >= tau

    // survivor count (ballot-based, wave-uniform)
    int c = 0;
    #pragma unroll
    for (int i = 0; i < 16; ++i) c += __popcll(__ballot(key[i] >= tau));

    const bool fb = (c > CAPW);
    unsigned T = 0, istar = 0;
    if (fb) {
        // exact fallback: key-bit radix (multi-count -> shuffle reduce), then idx radix
        int need = WID;
        unsigned prefix = 0;
        for (int b = 31; b >= 0; --b) {
            unsigned pb1 = (prefix >> b) | 1u;
            int c1 = 0;
            #pragma unroll
            for (int i = 0; i < 16; ++i) c1 += ((key[i] >> b) == pb1) ? 1 : 0;
            #pragma unroll
            for (int off = 32; off; off >>= 1) c1 += __shfl_xor(c1, off);
            if (c1 >= need) prefix |= (1u << b);
            else need -= c1;
        }
        T = prefix;
        for (int b = 9; b >= 0; --b) {          // v_local < 1024 -> 10 bits
            int c0 = 0;
            #pragma unroll
            for (int i = 0; i < 16; ++i) {
                unsigned vv = (unsigned)(4*lane + 256*(i >> 2) + (i & 3));
                if (key[i] == T && (vv >> (b+1)) == (istar >> (b+1)) && !((vv >> b) & 1u)) c0++;
            }
            #pragma unroll
            for (int off = 32; off; off >>= 1) c0 += __shfl_xor(c0, off);
            if (c0 >= need) { } else { need -= c0; istar |= (1u << b); }
        }
    }
    const int wcount = fb ? WID : c;

    // wave base in block list
    int base = 0;
    if (lane == 0) base = atomicAdd(&s_cnt, wcount);
    base = __shfl(base, 0);

    // gather via ballot + mbcnt (deterministic within wave; list order irrelevant)
    const unsigned long long lmask = (1ull << lane) - 1ull;
    int off = base;
    #pragma unroll
    for (int i = 0; i < 16; ++i) {
        unsigned vv = (unsigned)(4*lane + 256*(i >> 2) + (i & 3));
        bool sel = fb ? (key[i] > T || (key[i] == T && vv <= istar))
                      : (key[i] >= tau);
        unsigned long long msk = __ballot(sel);
        int my = __popcll(msk & lmask);
        if (sel) {
            int slot = off + my;
            s_lf[slot] = key[i];
            s_li[slot] = (k << 11) + (half << 10) + (int)vv;
        }
        off += __popcll(msk);
    }
    __syncthreads();

    // single block rank-sort over cc (~172) -> block top-32 sorted to ws
    const int cc = s_cnt;
    for (int e = tid; e < cc; e += 256) {
        unsigned mf = s_lf[e]; int mi = s_li[e];
        int rank = 0;
        for (int j2 = 0; j2 < cc; ++j2) {
            unsigned fq = s_lf[j2];
            rank += (fq > mf || (fq == mf && s_li[j2] < mi)) ? 1 : 0;
        }
        if (rank < WID) { wsF[blk*WID + rank] = mf; wsI[blk*WID + rank] = mi; }
    }
}

// ---------------- kernel B: merge (tau-filtered) + epilogue + prefix + y_next ----------------
__global__ __launch_bounds__(256) void merge_kernel(
    const float* __restrict__ nonext,
    const float* __restrict__ blank,
    const float* __restrict__ nbp_g,
    const float* __restrict__ bp_g,
    const int*   __restrict__ yprev,
    const int*   __restrict__ ylast,
    const int*   __restrict__ ylens,
    const int*   __restrict__ pip,
    const unsigned* __restrict__ wsF, const int* __restrict__ wsI,
    const float* __restrict__ wsAb,
    float* __restrict__ out)
{
    const int n   = blockIdx.x;
    const int tid = threadIdx.x;

    __shared__ int      s_last[KPP];
    __shared__ float    s_bne[KPP], s_nbne[KPP];
    __shared__ float    s_abL[KPP][KPP];
    __shared__ unsigned s_cf[NLIST];
    __shared__ int      s_ci[NLIST];
    __shared__ unsigned s_ff[NLIST];
    __shared__ int      s_fi[NLIST];
    __shared__ unsigned long long s_tau;
    __shared__ int      s_cnt;
    __shared__ int      s_selidx[WID];
    __shared__ float    s_selval[WID];
    __shared__ int      s_r_src[WID], s_r_lens[WID], s_r_ext[WID], s_r_noext[WID];

    if (tid == 0) s_cnt = 0;
    if (tid < KPP) {
        int k = tid;
        int last = ylast[n*KPP + k]; last = min(max(last, 0), VV-1);
        float a = nbp_g[n*KPP + k], b = bp_g[n*KPP + k];
        s_last[k] = last;
        s_bne[k]  = (a + b) * blank[n];
        s_nbne[k] = a * nonext[(size_t)n*VV + last];
    }
    // stage absorb terms (coalesced) while scalars land
    for (int i = tid; i < KPP*KPP; i += 256)
        s_abL[i >> 5][i & 31] = wsAb[(size_t)n*KPP*KPP + i];
    __syncthreads();
    if (tid < KPP) {    // serial k-order sum (bit-exact; zero terms are bitwise-neutral)
        int j = tid;
        float acc = s_nbne[j];
        #pragma unroll
        for (int k = 0; k < KPP; ++k) acc += s_abL[k][j];
        s_nbne[j] = acc;
    }
    __syncthreads();

    // merge list: 512 block winners + 32 nonext
    for (int i = tid; i < NLIST; i += 256) {
        if (i < KBLK*WID) {
            s_cf[i] = wsF[n*KBLK*WID + i];
            s_ci[i] = wsI[n*KBLK*WID + i];
        } else {
            int j = i - KBLK*WID;
            s_cf[i] = fkey(s_nbne[j] + s_bne[j]);
            s_ci[i] = NEXT_BASE + j;
        }
    }
    __syncthreads();

    // tau = max over blocks of their 32nd packed key (lower bound on global 32nd)
    if (tid < 64) {
        unsigned long long p = 0ull;
        if (tid < KBLK) {
            int i = tid*WID + (WID-1);
            p = ((unsigned long long)s_cf[i] << 32) | (unsigned)(~s_ci[i]);
        }
        #pragma unroll
        for (int off = 32; off; off >>= 1) {
            unsigned long long o = shflx64(p, off);
            if (o > p) p = o;
        }
        if (tid == 0) s_tau = p;
    }
    __syncthreads();
    const unsigned long long tau = s_tau;

    for (int i = tid; i < NLIST; i += 256) {
        unsigned long long p = ((unsigned long long)s_cf[i] << 32) | (unsigned)(~s_ci[i]);
        if (p >= tau) {
            int slot = atomicAdd(&s_cnt, 1);
            s_ff[slot] = s_cf[i]; s_fi[slot] = s_ci[i];
        }
    }
    __syncthreads();
    const int cc = s_cnt;

    for (int e = tid; e < cc; e += 256) {
        unsigned mf = s_ff[e]; int mi = s_fi[e];
        int rank = 0;
        for (int j = 0; j < cc; ++j) {
            unsigned f = s_ff[j];
            rank += (f > mf || (f == mf && s_fi[j] < mi)) ? 1 : 0;
        }
        if (rank < WID) { s_selidx[rank] = mi; s_selval[rank] = funkey(mf); }
    }
    __syncthreads();

    // epilogue: per-k scalar outputs
    if (tid < WID) {
        int k = tid;
        int ind = s_selidx[k];
        bool noext = ind >= NEXT_BASE;
        int src  = noext ? (ind - NEXT_BASE) : (ind >> 11);
        int extk = ind & (VV-1);
        int plen = ylens[n*KPP + src];
        int lens = plen + (noext ? 0 : 1);
        float nbv = noext ? s_nbne[src] : s_selval[k];
        float bv  = noext ? s_bne[src]  : 0.0f;
        int lastv = noext ? s_last[src] : extk;
        size_t o = (size_t)n*WID + k;
        out[O_LAST  + o] = (float)lastv;
        out[O_LENS  + o] = (float)lens;
        out[O_NB    + o] = nbv;
        out[O_B     + o] = bv;
        out[O_SRC   + o] = (float)src;
        out[O_NOEXT + o] = noext ? 1.0f : 0.0f;
        s_r_src[k] = src; s_r_lens[k] = lens; s_r_ext[k] = extk;
        s_r_noext[k] = noext ? 1 : 0;
    }
    __syncthreads();

    // fused next_is_prefix (all 1024 (k,j) pairs with 256 threads)
    for (int i = tid; i < WID*WID; i += 256) {
        int k = i >> 5, j = i & 31;
        int src_j = s_r_src[j];
        int no_k  = s_r_noext[k], no_j = s_r_noext[j];
        int lens_k = s_r_lens[k], lens_j = s_r_lens[j];
        int plen_j = lens_j - (no_j ? 0 : 1);
        bool prefix = pip[((size_t)n*KPP + s_r_src[k])*KPP + src_j] != 0;
        bool leq    = lens_k <= lens_j;
        int  tstar  = max(lens_k - 1, 0);
        int  tmj;
        if (tstar == plen_j)   tmj = s_r_ext[j];
        else if (tstar < SS)   tmj = yprev[((size_t)tstar*NB + n)*KPP + src_j];
        else                   tmj = 0;
        bool res = prefix && leq && (no_k || (tmj == s_r_ext[k]));
        out[O_PREF + (size_t)n*WID*WID + i] = res ? 1.0f : 0.0f;
    }

    // fused y_next: out[t][n][k]
    for (int id = tid; id < (SS+1)*WID; id += 256) {
        int t = id >> 5, kq = id & 31;
        int src  = s_r_src[kq];
        int plen = s_r_lens[kq] - (s_r_noext[kq] ? 0 : 1);
        float val;
        if (t == plen)   val = (float)s_r_ext[kq];
        else if (t < SS) val = (float)yprev[((size_t)t*NB + n)*KPP + src];
        else             val = 0.0f;
        out[(size_t)t*NK + (size_t)n*WID + kq] = val;
    }
}

extern "C" void kernel_launch(void* const* d_in, const int* in_sizes, int n_in,
                              void* d_out, int out_size, void* d_ws, size_t ws_size,
                              hipStream_t stream) {
    const float* ext    = (const float*)d_in[0];
    const float* nonext = (const float*)d_in[1];
    const float* blank  = (const float*)d_in[2];
    const float* nbp    = (const float*)d_in[3];
    const float* bp     = (const float*)d_in[4];
    const int*   yprev  = (const int*)d_in[5];
    const int*   ylast  = (const int*)d_in[6];
    const int*   ylens  = (const int*)d_in[7];
    const int*   pip    = (const int*)d_in[8];
    float* out = (float*)d_out;

    unsigned* wsF  = (unsigned*)d_ws;                      // NB*KBLK*WID u32   (256 KB)
    int*      wsI  = (int*)d_ws + NB*KBLK*WID;             // +256 KB
    float*    wsAb = (float*)d_ws + 2*NB*KBLK*WID;         // NB*KPP*KPP floats (512 KB)

    slice_topk_kernel<<<NB*KBLK, 256, 0, stream>>>(ext, nbp, bp, yprev, ylast,
                                                   ylens, pip, wsF, wsI, wsAb);
    merge_kernel<<<NB, 256, 0, stream>>>(nonext, blank, nbp, bp,
                                         yprev, ylast, ylens, pip, wsF, wsI, wsAb, out);
}

// Round 10
// 53.140 us; speedup vs baseline: 1.0840x; 1.0840x over previous
//
#include <hip/hip_runtime.h>
#include <cstdint>
#include <cstddef>

#define NB 128      // N
#define KPP 32      // Kp
#define VV 2048     // V
#define SS 200      // S (tm1)
#define WID 32      // width == K
#define NEXT_BASE (KPP*VV)     // 65536
#define KBLK 16                // blocks per n (each block = 4 waves = 2 rows x 2 halves)
#define CAPW 128               // per-wave survivor cap
#define NWAVE (KPP*2)          // 64 waves per n
#define NLIST (NWAVE*WID + WID) // 2080 merge candidates

// output layout (flat f32, concat in return order)
#define SZ_YNEXT ((size_t)(SS+1)*NB*WID)               // 823296
#define NK       ((size_t)NB*WID)                      // 4096
#define O_LAST   (SZ_YNEXT)
#define O_LENS   (SZ_YNEXT + NK)
#define O_NB     (SZ_YNEXT + 2*NK)
#define O_B      (SZ_YNEXT + 3*NK)
#define O_PREF   (SZ_YNEXT + 4*NK)                     // size NB*WID*WID
#define O_SRC    (SZ_YNEXT + 4*NK + (size_t)NB*WID*WID)
#define O_NOEXT  (SZ_YNEXT + 5*NK + (size_t)NB*WID*WID)

__device__ __forceinline__ unsigned fkey(float f) {
    unsigned u = __float_as_uint(f);
    return (u & 0x80000000u) ? ~u : (u | 0x80000000u);
}
__device__ __forceinline__ float funkey(unsigned k) {
    unsigned u = (k & 0x80000000u) ? (k & 0x7FFFFFFFu) : ~k;
    return __uint_as_float(u);
}
__device__ __forceinline__ unsigned long long shflx64(unsigned long long v, int m) {
    int lo = __shfl_xor((int)(unsigned)v, m);
    int hi = __shfl_xor((int)(unsigned)(v >> 32), m);
    return ((unsigned long long)(unsigned)hi << 32) | (unsigned)lo;
}

// ---------------- kernel A: one wave per HALF k-row, fully wave-autonomous ----------------
__global__ __launch_bounds__(256) void slice_topk_kernel(
    const float* __restrict__ ext,     // [N][Kp][V]
    const float* __restrict__ nbp_g,   // [N][Kp]
    const float* __restrict__ bp_g,    // [N][Kp]
    const int*   __restrict__ yprev,   // [S][N][Kp]
    const int*   __restrict__ ylast,   // [N][Kp]
    const int*   __restrict__ ylens,   // [N][Kp]
    const int*   __restrict__ pip,     // [N][Kp][Kp]
    unsigned* __restrict__ wsF, int* __restrict__ wsI, float* __restrict__ wsAb)
{
    const int blk  = blockIdx.x;
    const int n    = blk >> 4;          // KBLK = 16
    const int kb   = blk & 15;
    const int tid  = threadIdx.x;
    const int w    = tid >> 6;          // 4 waves
    const int lane = tid & 63;
    const int k    = kb*2 + (w >> 1);
    const int half = w & 1;
    const int g    = ((n*KPP + k) << 1) + half;   // this wave's ws slot

    __shared__ unsigned s_hm[4][VV/32];     // wave-private hm (full row), 1 KB
    __shared__ unsigned s_bk[4][CAPW];      // wave-private survivor buffers
    __shared__ int      s_bi[4][CAPW];

    s_hm[w][lane] = 0u;                 // VV/32 == 64 == lane count (wave-private)

    // per-row params (wave-uniform addresses -> broadcast loads)
    const int   tlen = ylens[n*KPP + k];
    int last = ylast[n*KPP + k]; last = min(max(last, 0), VV-1);
    const float nbp = nbp_g[n*KPP + k];
    const float bp  = bp_g[n*KPP + k];

    // issue the 4 float4 loads early (16 floats/lane, registers only)
    const float4* g4 = (const float4*)(ext + ((size_t)n*KPP + k)*VV + half*1024);
    float4 f[4];
    #pragma unroll
    for (int j = 0; j < 4; ++j) f[j] = g4[lane + 64*j];

    // has-match bits + absorb terms (same-wave LDS ordering; no barrier needed)
    if (lane < KPP) {
        int j = lane;
        int tcl = min(max(tlen, 0), SS-1);
        int tm  = yprev[((size_t)tcl*NB + n)*KPP + j];
        tm = min(max(tm, 0), VV-1);
        bool ex = (tlen + 1 == ylens[n*KPP + j]) && (pip[((size_t)n*KPP + k)*KPP + j] != 0);
        if (ex) atomicOr(&s_hm[w][tm >> 5], 1u << (tm & 31));
        if (half == 0) {
            float ev = ex ? ext[((size_t)n*KPP + k)*VV + tm] : 0.0f;
            float bb = (tm == last) ? 0.0f : nbp;
            wsAb[((size_t)n*KPP + k)*KPP + j] = ex ? (bb + bp)*ev : 0.0f;
        }
    }

    // 16 keys in registers; v_local = 4*lane + 256*j + e in [0,1024)
    unsigned key[16];
    #pragma unroll
    for (int j = 0; j < 4; ++j) {
        const float fe[4] = {f[j].x, f[j].y, f[j].z, f[j].w};
        #pragma unroll
        for (int e = 0; e < 4; ++e) {
            int vl = 4*lane + 256*j + e;
            int v  = (half << 10) + vl;
            float base = (v == last) ? 0.0f : nbp;
            float val  = (base + bp) * fe[e];
            if ((s_hm[w][v >> 5] >> (v & 31)) & 1u) val = -INFINITY;
            key[j*4 + e] = fkey(val);
        }
    }

    // lane max
    unsigned m = key[0];
    #pragma unroll
    for (int i = 1; i < 16; ++i) m = max(m, key[i]);

    // tau = EXACT 32nd-largest of the 64 lane maxima (ballot radix, scalar pipe)
    unsigned tau = 0;
    {
        int need = 32;
        #pragma unroll
        for (int b = 31; b >= 0; --b) {
            unsigned pb1 = (tau >> b) | 1u;
            unsigned long long msk = __ballot((m >> b) == pb1);
            int cnt = __popcll(msk);
            if (cnt >= need) tau |= (1u << b);
            else             need -= cnt;
        }
    }
    // guarantee: >=32 lanes have m >= tau  =>  >=32 keys >= tau

    // survivor count (ballot-based, wave-uniform)
    int c = 0;
    #pragma unroll
    for (int i = 0; i < 16; ++i) c += __popcll(__ballot(key[i] >= tau));

    const bool fb = (c > CAPW);
    unsigned T = 0, istar = 0;
    if (fb) {
        // exact fallback: key-bit radix, then idx radix among ties (shuffle-only)
        int need = WID;
        unsigned prefix = 0;
        for (int b = 31; b >= 0; --b) {
            unsigned pb1 = (prefix >> b) | 1u;
            int c1 = 0;
            #pragma unroll
            for (int i = 0; i < 16; ++i) c1 += ((key[i] >> b) == pb1) ? 1 : 0;
            #pragma unroll
            for (int off = 32; off; off >>= 1) c1 += __shfl_xor(c1, off);
            if (c1 >= need) prefix |= (1u << b);
            else need -= c1;
        }
        T = prefix;
        for (int b = 9; b >= 0; --b) {          // v_local < 1024 -> 10 bits
            int c0 = 0;
            #pragma unroll
            for (int i = 0; i < 16; ++i) {
                unsigned vv = (unsigned)(4*lane + 256*(i >> 2) + (i & 3));
                if (key[i] == T && (vv >> (b+1)) == (istar >> (b+1)) && !((vv >> b) & 1u)) c0++;
            }
            #pragma unroll
            for (int off = 32; off; off >>= 1) c0 += __shfl_xor(c0, off);
            if (c0 >= need) { } else { need -= c0; istar |= (1u << b); }
        }
    }

    // gather survivors via ballot prefix into wave-private LDS (base 0, no atomics)
    const unsigned long long lmask = (1ull << lane) - 1ull;
    int off2 = 0;
    #pragma unroll
    for (int i = 0; i < 16; ++i) {
        unsigned vv = (unsigned)(4*lane + 256*(i >> 2) + (i & 3));
        bool sel = fb ? (key[i] > T || (key[i] == T && vv <= istar))
                      : (key[i] >= tau);
        unsigned long long msk = __ballot(sel);
        int my = __popcll(msk & lmask);
        if (sel) {
            int slot = off2 + my;
            if (slot < CAPW) {
                s_bk[w][slot] = key[i];
                s_bi[w][slot] = (k << 11) + (half << 10) + (int)vv;
            }
        }
        off2 += __popcll(msk);
    }
    const int total = fb ? WID : c;

    // in-wave rank-sort (~43 elements); write this wave's sorted top-32 to ws
    for (int e = lane; e < total; e += 64) {
        unsigned mf = s_bk[w][e]; int mi = s_bi[w][e];
        int rank = 0;
        for (int j2 = 0; j2 < total; ++j2) {
            unsigned fq = s_bk[w][j2];
            rank += (fq > mf || (fq == mf && s_bi[w][j2] < mi)) ? 1 : 0;
        }
        if (rank < WID) { wsF[g*WID + rank] = mf; wsI[g*WID + rank] = mi; }
    }
}

// ---------------- kernel B: merge (tau-filtered over 64 wave-lists) + epilogue ----------------
__global__ __launch_bounds__(256) void merge_kernel(
    const float* __restrict__ nonext,
    const float* __restrict__ blank,
    const float* __restrict__ nbp_g,
    const float* __restrict__ bp_g,
    const int*   __restrict__ ylast,
    const int*   __restrict__ ylens,
    const unsigned* __restrict__ wsF, const int* __restrict__ wsI,
    const float* __restrict__ wsAb,
    float* __restrict__ out)
{
    const int n   = blockIdx.x;
    const int tid = threadIdx.x;

    __shared__ int      s_last[KPP];
    __shared__ float    s_bne[KPP], s_nbne[KPP];
    __shared__ float    s_abL[KPP][KPP];
    __shared__ unsigned s_cf[NLIST];
    __shared__ int      s_ci[NLIST];
    __shared__ unsigned s_ff[256];
    __shared__ int      s_fi[256];
    __shared__ unsigned long long s_tau;
    __shared__ int      s_cnt;
    __shared__ int      s_selidx[WID];
    __shared__ float    s_selval[WID];

    if (tid == 0) s_cnt = 0;
    if (tid < KPP) {
        int k = tid;
        int last = ylast[n*KPP + k]; last = min(max(last, 0), VV-1);
        float a = nbp_g[n*KPP + k], b = bp_g[n*KPP + k];
        s_last[k] = last;
        s_bne[k]  = (a + b) * blank[n];
        s_nbne[k] = a * nonext[(size_t)n*VV + last];
    }
    for (int i = tid; i < KPP*KPP; i += 256)
        s_abL[i >> 5][i & 31] = wsAb[(size_t)n*KPP*KPP + i];
    __syncthreads();
    if (tid < KPP) {    // serial k-order sum (bit-exact; zero terms bitwise-neutral)
        int j = tid;
        float acc = s_nbne[j];
        #pragma unroll
        for (int k = 0; k < KPP; ++k) acc += s_abL[k][j];
        s_nbne[j] = acc;
    }
    __syncthreads();

    // candidate list: 64 wave-top-32s + 32 nonext
    for (int i = tid; i < NLIST; i += 256) {
        if (i < NWAVE*WID) {
            s_cf[i] = wsF[(size_t)n*NWAVE*WID + i];
            s_ci[i] = wsI[(size_t)n*NWAVE*WID + i];
        } else {
            int j = i - NWAVE*WID;
            s_cf[i] = fkey(s_nbne[j] + s_bne[j]);
            s_ci[i] = NEXT_BASE + j;
        }
    }
    __syncthreads();

    // tau = max over waves of their 32nd packed key (lower bound on global 32nd)
    if (tid < 64) {
        int i = tid*WID + (WID-1);
        unsigned long long p = ((unsigned long long)s_cf[i] << 32) | (unsigned)(~s_ci[i]);
        #pragma unroll
        for (int off = 32; off; off >>= 1) {
            unsigned long long o = shflx64(p, off);
            if (o > p) p = o;
        }
        if (tid == 0) s_tau = p;
    }
    __syncthreads();
    const unsigned long long tau = s_tau;

    for (int i = tid; i < NLIST; i += 256) {
        unsigned long long p = ((unsigned long long)s_cf[i] << 32) | (unsigned)(~s_ci[i]);
        if (p >= tau) {
            int slot = atomicAdd(&s_cnt, 1);
            if (slot < 256) { s_ff[slot] = s_cf[i]; s_fi[slot] = s_ci[i]; }
        }
    }
    __syncthreads();
    int cc = s_cnt; if (cc > 256) cc = 256;   // >=32 guaranteed within cap (argmax wave's 32)

    for (int e = tid; e < cc; e += 256) {
        unsigned mf = s_ff[e]; int mi = s_fi[e];
        int rank = 0;
        for (int j = 0; j < cc; ++j) {
            unsigned f = s_ff[j];
            rank += (f > mf || (f == mf && s_fi[j] < mi)) ? 1 : 0;
        }
        if (rank < WID) { s_selidx[rank] = mi; s_selval[rank] = funkey(mf); }
    }
    __syncthreads();

    // epilogue: per-k scalar outputs
    if (tid < WID) {
        int k = tid;
        int ind = s_selidx[k];
        bool noext = ind >= NEXT_BASE;
        int src  = noext ? (ind - NEXT_BASE) : (ind >> 11);
        int extk = ind & (VV-1);
        int plen = ylens[n*KPP + src];
        int lens = plen + (noext ? 0 : 1);
        float nbv = noext ? s_nbne[src] : s_selval[k];
        float bv  = noext ? s_bne[src]  : 0.0f;
        int lastv = noext ? s_last[src] : extk;
        size_t o = (size_t)n*WID + k;
        out[O_LAST  + o] = (float)lastv;
        out[O_LENS  + o] = (float)lens;
        out[O_NB    + o] = nbv;
        out[O_B     + o] = bv;
        out[O_SRC   + o] = (float)src;
        out[O_NOEXT + o] = noext ? 1.0f : 0.0f;
    }
}

// ---------------- kernel C: y_next (full-chip; round-3-proven) ----------------
__global__ void ynext_kernel(const int* __restrict__ yprev, float* __restrict__ out) {
    int id = blockIdx.x*blockDim.x + threadIdx.x;
    if (id >= (int)SZ_YNEXT) return;
    int k = id & 31;
    int n = (id >> 5) & 127;
    int t = id >> 12;                    // NB*WID = 4096 = 2^12
    size_t o = (size_t)n*WID + k;
    int src    = (int)out[O_SRC + o];
    bool noext = out[O_NOEXT + o] != 0.0f;
    int lens   = (int)out[O_LENS + o];
    int plen   = lens - (noext ? 0 : 1);
    int extk   = noext ? src : (int)out[O_LAST + o];
    float val;
    if (t == plen)      val = (float)extk;
    else if (t < SS)    val = (float)yprev[((size_t)t*NB + n)*KPP + src];
    else                val = 0.0f;
    out[id] = val;
}

// ---------------- kernel D: next_is_prefix (full-width; round-3-proven) ----------------
__global__ void prefix_kernel(const int* __restrict__ yprev, const int* __restrict__ pip,
                              float* __restrict__ out) {
    int id = blockIdx.x*blockDim.x + threadIdx.x;   // N*32*32
    if (id >= NB*WID*WID) return;
    int j = id & 31;
    int k = (id >> 5) & 31;
    int n = id >> 10;
    size_t ok = (size_t)n*WID + k, oj = (size_t)n*WID + j;
    int  src_k = (int)out[O_SRC + ok];
    int  src_j = (int)out[O_SRC + oj];
    bool no_k  = out[O_NOEXT + ok] != 0.0f;
    bool no_j  = out[O_NOEXT + oj] != 0.0f;
    int  lens_k = (int)out[O_LENS + ok];
    int  lens_j = (int)out[O_LENS + oj];
    int  ext_k = no_k ? src_k : (int)out[O_LAST + ok];
    int  ext_j = no_j ? src_j : (int)out[O_LAST + oj];
    int  plen_j = lens_j - (no_j ? 0 : 1);
    bool prefix = pip[((size_t)n*KPP + src_k)*KPP + src_j] != 0;
    bool leq    = lens_k <= lens_j;
    int  tstar  = max(lens_k - 1, 0);
    int  tmj;
    if (tstar == plen_j)   tmj = ext_j;
    else if (tstar < SS)   tmj = yprev[((size_t)tstar*NB + n)*KPP + src_j];
    else                   tmj = 0;
    bool matches = (tmj == ext_k);
    bool res = prefix && leq && (no_k || matches);
    out[O_PREF + (size_t)n*WID*WID + (size_t)k*WID + j] = res ? 1.0f : 0.0f;
}

extern "C" void kernel_launch(void* const* d_in, const int* in_sizes, int n_in,
                              void* d_out, int out_size, void* d_ws, size_t ws_size,
                              hipStream_t stream) {
    const float* ext    = (const float*)d_in[0];
    const float* nonext = (const float*)d_in[1];
    const float* blank  = (const float*)d_in[2];
    const float* nbp    = (const float*)d_in[3];
    const float* bp     = (const float*)d_in[4];
    const int*   yprev  = (const int*)d_in[5];
    const int*   ylast  = (const int*)d_in[6];
    const int*   ylens  = (const int*)d_in[7];
    const int*   pip    = (const int*)d_in[8];
    float* out = (float*)d_out;

    unsigned* wsF  = (unsigned*)d_ws;                      // NB*64*32 u32 (1 MB)
    int*      wsI  = (int*)d_ws + NB*NWAVE*WID;            // +1 MB
    float*    wsAb = (float*)d_ws + 2*NB*NWAVE*WID;        // NB*KPP*KPP floats (512 KB)

    slice_topk_kernel<<<NB*KBLK, 256, 0, stream>>>(ext, nbp, bp, yprev, ylast,
                                                   ylens, pip, wsF, wsI, wsAb);
    merge_kernel<<<NB, 256, 0, stream>>>(nonext, blank, nbp, bp,
                                         ylast, ylens, wsF, wsI, wsAb, out);
    ynext_kernel<<<((int)SZ_YNEXT + 255)/256, 256, 0, stream>>>(yprev, out);
    prefix_kernel<<<(NB*WID*WID + 255)/256, 256, 0, stream>>>(yprev, pip, out);
}

// Round 11
// 46.527 us; speedup vs baseline: 1.2381x; 1.1421x over previous
//
#include <hip/hip_runtime.h>
#include <cstdint>
#include <cstddef>

#define NB 128      // N
#define KPP 32      // Kp
#define VV 2048     // V
#define SS 200      // S (tm1)
#define WID 32      // width == K
#define NEXT_BASE (KPP*VV)     // 65536
#define KBLK 16                // blocks per n (each block = 4 waves = 2 rows x 2 halves)
#define CAPW 128               // per-wave survivor cap
#define NWAVE (KPP*2)          // 64 waves per n
#define NLIST (NWAVE*WID + WID) // 2080 merge candidates
#define FCAP 256               // merge filtered-list cap (overflow -> exact full rank)

// output layout (flat f32, concat in return order)
#define SZ_YNEXT ((size_t)(SS+1)*NB*WID)               // 823296
#define NK       ((size_t)NB*WID)                      // 4096
#define O_LAST   (SZ_YNEXT)
#define O_LENS   (SZ_YNEXT + NK)
#define O_NB     (SZ_YNEXT + 2*NK)
#define O_B      (SZ_YNEXT + 3*NK)
#define O_PREF   (SZ_YNEXT + 4*NK)                     // size NB*WID*WID
#define O_SRC    (SZ_YNEXT + 4*NK + (size_t)NB*WID*WID)
#define O_NOEXT  (SZ_YNEXT + 5*NK + (size_t)NB*WID*WID)
#define SZ_PREF  ((size_t)NB*WID*WID)                  // 131072

__device__ __forceinline__ unsigned fkey(float f) {
    unsigned u = __float_as_uint(f);
    return (u & 0x80000000u) ? ~u : (u | 0x80000000u);
}
__device__ __forceinline__ float funkey(unsigned k) {
    unsigned u = (k & 0x80000000u) ? (k & 0x7FFFFFFFu) : ~k;
    return __uint_as_float(u);
}
__device__ __forceinline__ unsigned long long shflx64(unsigned long long v, int m) {
    int lo = __shfl_xor((int)(unsigned)v, m);
    int hi = __shfl_xor((int)(unsigned)(v >> 32), m);
    return ((unsigned long long)(unsigned)hi << 32) | (unsigned)lo;
}

// ---------------- kernel A: one wave per HALF k-row, fully wave-autonomous ----------------
__global__ __launch_bounds__(256) void slice_topk_kernel(
    const float* __restrict__ ext,     // [N][Kp][V]
    const float* __restrict__ nbp_g,   // [N][Kp]
    const float* __restrict__ bp_g,    // [N][Kp]
    const int*   __restrict__ yprev,   // [S][N][Kp]
    const int*   __restrict__ ylast,   // [N][Kp]
    const int*   __restrict__ ylens,   // [N][Kp]
    const int*   __restrict__ pip,     // [N][Kp][Kp]
    unsigned* __restrict__ wsF, int* __restrict__ wsI, float* __restrict__ wsAb)
{
    const int blk  = blockIdx.x;
    const int n    = blk >> 4;          // KBLK = 16
    const int kb   = blk & 15;
    const int tid  = threadIdx.x;
    const int w    = tid >> 6;          // 4 waves
    const int lane = tid & 63;
    const int k    = kb*2 + (w >> 1);
    const int half = w & 1;
    const int g    = ((n*KPP + k) << 1) + half;   // this wave's ws slot

    __shared__ unsigned s_hm[4][VV/32];     // wave-private hm (full row), 1 KB
    __shared__ unsigned s_bk[4][CAPW];      // wave-private survivor buffers
    __shared__ int      s_bi[4][CAPW];

    s_hm[w][lane] = 0u;                 // VV/32 == 64 == lane count (wave-private)

    // per-row params (wave-uniform addresses -> broadcast loads)
    const int   tlen = ylens[n*KPP + k];
    int last = ylast[n*KPP + k]; last = min(max(last, 0), VV-1);
    const float nbp = nbp_g[n*KPP + k];
    const float bp  = bp_g[n*KPP + k];

    // issue the 4 float4 loads early (16 floats/lane, registers only)
    const float4* g4 = (const float4*)(ext + ((size_t)n*KPP + k)*VV + half*1024);
    float4 f[4];
    #pragma unroll
    for (int j = 0; j < 4; ++j) f[j] = g4[lane + 64*j];

    // has-match bits + absorb terms (same-wave LDS ordering; no barrier needed)
    if (lane < KPP) {
        int j = lane;
        int tcl = min(max(tlen, 0), SS-1);
        int tm  = yprev[((size_t)tcl*NB + n)*KPP + j];
        tm = min(max(tm, 0), VV-1);
        bool ex = (tlen + 1 == ylens[n*KPP + j]) && (pip[((size_t)n*KPP + k)*KPP + j] != 0);
        if (ex) atomicOr(&s_hm[w][tm >> 5], 1u << (tm & 31));
        if (half == 0) {
            float ev = ex ? ext[((size_t)n*KPP + k)*VV + tm] : 0.0f;
            float bb = (tm == last) ? 0.0f : nbp;
            wsAb[((size_t)n*KPP + k)*KPP + j] = ex ? (bb + bp)*ev : 0.0f;
        }
    }

    // 16 keys in registers; v_local = 4*lane + 256*j + e in [0,1024)
    unsigned key[16];
    #pragma unroll
    for (int j = 0; j < 4; ++j) {
        const float fe[4] = {f[j].x, f[j].y, f[j].z, f[j].w};
        #pragma unroll
        for (int e = 0; e < 4; ++e) {
            int vl = 4*lane + 256*j + e;
            int v  = (half << 10) + vl;
            float base = (v == last) ? 0.0f : nbp;
            float val  = (base + bp) * fe[e];
            if ((s_hm[w][v >> 5] >> (v & 31)) & 1u) val = -INFINITY;
            key[j*4 + e] = fkey(val);
        }
    }

    // lane max (top 16 bits suffice for the threshold)
    unsigned m = key[0];
    #pragma unroll
    for (int i = 1; i < 16; ++i) m = max(m, key[i]);
    const unsigned m16 = m >> 16;

    // tau16 = EXACT 32nd-largest of the 64 (lane-max >> 16) values: 16 ballot steps
    unsigned tau16 = 0;
    {
        int need = 32;
        #pragma unroll
        for (int b = 15; b >= 0; --b) {
            unsigned pb1 = (tau16 >> b) | 1u;
            unsigned long long msk = __ballot((m16 >> b) == pb1);
            int cnt = __popcll(msk);
            if (cnt >= need) tau16 |= (1u << b);
            else             need -= cnt;
        }
    }
    // guarantee: >=32 lanes have (m>>16) >= tau16  =>  >=32 keys with (key>>16) >= tau16

    // optimistic gather (no separate count phase); c accumulates via ballot prefix
    const unsigned long long lmask = (1ull << lane) - 1ull;
    int off2 = 0;
    #pragma unroll
    for (int i = 0; i < 16; ++i) {
        bool sel = (key[i] >> 16) >= tau16;
        unsigned long long msk = __ballot(sel);
        if (sel) {
            int slot = off2 + __popcll(msk & lmask);
            if (slot < CAPW) {
                s_bk[w][slot] = key[i];
                s_bi[w][slot] = (k << 11) + (half << 10) + (4*lane + 256*(i >> 2) + (i & 3));
            }
        }
        off2 += __popcll(msk);
    }
    int total = off2;

    if (total > CAPW) {
        // exact fallback: key-bit radix, then idx radix among ties (shuffle-only)
        int need = WID;
        unsigned T = 0, istar = 0;
        for (int b = 31; b >= 0; --b) {
            unsigned pb1 = (T >> b) | 1u;
            int c1 = 0;
            #pragma unroll
            for (int i = 0; i < 16; ++i) c1 += ((key[i] >> b) == pb1) ? 1 : 0;
            #pragma unroll
            for (int off = 32; off; off >>= 1) c1 += __shfl_xor(c1, off);
            if (c1 >= need) T |= (1u << b);
            else need -= c1;
        }
        for (int b = 9; b >= 0; --b) {          // v_local < 1024 -> 10 bits
            int c0 = 0;
            #pragma unroll
            for (int i = 0; i < 16; ++i) {
                unsigned vv = (unsigned)(4*lane + 256*(i >> 2) + (i & 3));
                if (key[i] == T && (vv >> (b+1)) == (istar >> (b+1)) && !((vv >> b) & 1u)) c0++;
            }
            #pragma unroll
            for (int off = 32; off; off >>= 1) c0 += __shfl_xor(c0, off);
            if (c0 >= need) { } else { need -= c0; istar |= (1u << b); }
        }
        int o2 = 0;
        #pragma unroll
        for (int i = 0; i < 16; ++i) {
            unsigned vv = (unsigned)(4*lane + 256*(i >> 2) + (i & 3));
            bool sel = (key[i] > T || (key[i] == T && vv <= istar));
            unsigned long long msk = __ballot(sel);
            if (sel) {
                int slot = o2 + __popcll(msk & lmask);
                s_bk[w][slot] = key[i];
                s_bi[w][slot] = (k << 11) + (half << 10) + (int)vv;
            }
            o2 += __popcll(msk);
        }
        total = WID;    // exactly 32 selected
    }

    // in-wave rank-sort (~43 elements); write this wave's sorted top-32 to ws
    for (int e = lane; e < total; e += 64) {
        unsigned mf = s_bk[w][e]; int mi = s_bi[w][e];
        int rank = 0;
        for (int j2 = 0; j2 < total; ++j2) {
            unsigned fq = s_bk[w][j2];
            rank += (fq > mf || (fq == mf && s_bi[w][j2] < mi)) ? 1 : 0;
        }
        if (rank < WID) { wsF[g*WID + rank] = mf; wsI[g*WID + rank] = mi; }
    }
}

// ---------------- kernel B: merge (tau-filtered, overflow-exact) + epilogue ----------------
__global__ __launch_bounds__(256) void merge_kernel(
    const float* __restrict__ nonext,
    const float* __restrict__ blank,
    const float* __restrict__ nbp_g,
    const float* __restrict__ bp_g,
    const int*   __restrict__ ylast,
    const int*   __restrict__ ylens,
    const unsigned* __restrict__ wsF, const int* __restrict__ wsI,
    const float* __restrict__ wsAb,
    float* __restrict__ out)
{
    const int n   = blockIdx.x;
    const int tid = threadIdx.x;

    __shared__ int      s_last[KPP];
    __shared__ float    s_bne[KPP], s_nbne[KPP];
    __shared__ float    s_abL[KPP][KPP];
    __shared__ unsigned s_cf[NLIST];
    __shared__ int      s_ci[NLIST];
    __shared__ unsigned s_ff[FCAP];
    __shared__ int      s_fi[FCAP];
    __shared__ unsigned long long s_tau;
    __shared__ int      s_cnt;
    __shared__ int      s_selidx[WID];
    __shared__ float    s_selval[WID];

    if (tid == 0) s_cnt = 0;
    if (tid < KPP) {
        int k = tid;
        int last = ylast[n*KPP + k]; last = min(max(last, 0), VV-1);
        float a = nbp_g[n*KPP + k], b = bp_g[n*KPP + k];
        s_last[k] = last;
        s_bne[k]  = (a + b) * blank[n];
        s_nbne[k] = a * nonext[(size_t)n*VV + last];
    }
    for (int i = tid; i < KPP*KPP; i += 256)
        s_abL[i >> 5][i & 31] = wsAb[(size_t)n*KPP*KPP + i];
    __syncthreads();
    if (tid < KPP) {    // serial k-order sum (bit-exact; zero terms bitwise-neutral)
        int j = tid;
        float acc = s_nbne[j];
        #pragma unroll
        for (int k = 0; k < KPP; ++k) acc += s_abL[k][j];
        s_nbne[j] = acc;
    }
    __syncthreads();

    // candidate list: 64 wave-top-32s + 32 nonext
    for (int i = tid; i < NLIST; i += 256) {
        if (i < NWAVE*WID) {
            s_cf[i] = wsF[(size_t)n*NWAVE*WID + i];
            s_ci[i] = wsI[(size_t)n*NWAVE*WID + i];
        } else {
            int j = i - NWAVE*WID;
            s_cf[i] = fkey(s_nbne[j] + s_bne[j]);
            s_ci[i] = NEXT_BASE + j;
        }
    }
    __syncthreads();

    // tau = max over waves of their 32nd packed key (lower bound on global 32nd)
    if (tid < 64) {
        int i = tid*WID + (WID-1);
        unsigned long long p = ((unsigned long long)s_cf[i] << 32) | (unsigned)(~s_ci[i]);
        #pragma unroll
        for (int off = 32; off; off >>= 1) {
            unsigned long long o = shflx64(p, off);
            if (o > p) p = o;
        }
        if (tid == 0) s_tau = p;
    }
    __syncthreads();
    const unsigned long long tau = s_tau;

    for (int i = tid; i < NLIST; i += 256) {
        unsigned long long p = ((unsigned long long)s_cf[i] << 32) | (unsigned)(~s_ci[i]);
        if (p >= tau) {
            int slot = atomicAdd(&s_cnt, 1);
            if (slot < FCAP) { s_ff[slot] = s_cf[i]; s_fi[slot] = s_ci[i]; }
        }
    }
    __syncthreads();
    const int fcnt = s_cnt;

    if (fcnt <= FCAP) {
        // fast path: rank-sort the filtered (~35-65) list
        for (int e = tid; e < fcnt; e += 256) {
            unsigned mf = s_ff[e]; int mi = s_fi[e];
            int rank = 0;
            for (int j = 0; j < fcnt; ++j) {
                unsigned f = s_ff[j];
                rank += (f > mf || (f == mf && s_fi[j] < mi)) ? 1 : 0;
            }
            if (rank < WID) { s_selidx[rank] = mi; s_selval[rank] = funkey(mf); }
        }
    } else {
        // overflow (adversarial ties): exact rank over the FULL staged 2080 list
        for (int e = tid; e < NLIST; e += 256) {
            unsigned mf = s_cf[e]; int mi = s_ci[e];
            int rank = 0;
            for (int j = 0; j < NLIST; ++j) {
                unsigned f = s_cf[j];
                rank += (f > mf || (f == mf && s_ci[j] < mi)) ? 1 : 0;
            }
            if (rank < WID) { s_selidx[rank] = mi; s_selval[rank] = funkey(mf); }
        }
    }
    __syncthreads();

    // epilogue: per-k scalar outputs
    if (tid < WID) {
        int k = tid;
        int ind = s_selidx[k];
        bool noext = ind >= NEXT_BASE;
        int src  = noext ? (ind - NEXT_BASE) : (ind >> 11);
        int extk = ind & (VV-1);
        int plen = ylens[n*KPP + src];
        int lens = plen + (noext ? 0 : 1);
        float nbv = noext ? s_nbne[src] : s_selval[k];
        float bv  = noext ? s_bne[src]  : 0.0f;
        int lastv = noext ? s_last[src] : extk;
        size_t o = (size_t)n*WID + k;
        out[O_LAST  + o] = (float)lastv;
        out[O_LENS  + o] = (float)lens;
        out[O_NB    + o] = nbv;
        out[O_B     + o] = bv;
        out[O_SRC   + o] = (float)src;
        out[O_NOEXT + o] = noext ? 1.0f : 0.0f;
    }
}

// ---------------- kernel C: fused y_next + next_is_prefix (full-chip) ----------------
__global__ void epilogue_kernel(const int* __restrict__ yprev, const int* __restrict__ pip,
                                float* __restrict__ out) {
    int id = blockIdx.x*blockDim.x + threadIdx.x;
    if (id < (int)SZ_YNEXT) {
        int k = id & 31;
        int n = (id >> 5) & 127;
        int t = id >> 12;                    // NB*WID = 4096 = 2^12
        size_t o = (size_t)n*WID + k;
        int src    = (int)out[O_SRC + o];
        bool noext = out[O_NOEXT + o] != 0.0f;
        int lens   = (int)out[O_LENS + o];
        int plen   = lens - (noext ? 0 : 1);
        int extk   = noext ? src : (int)out[O_LAST + o];
        float val;
        if (t == plen)      val = (float)extk;
        else if (t < SS)    val = (float)yprev[((size_t)t*NB + n)*KPP + src];
        else                val = 0.0f;
        out[id] = val;
    } else if (id < (int)(SZ_YNEXT + SZ_PREF)) {
        int pid = id - (int)SZ_YNEXT;
        int j = pid & 31;
        int k = (pid >> 5) & 31;
        int n = pid >> 10;
        size_t ok = (size_t)n*WID + k, oj = (size_t)n*WID + j;
        int  src_k = (int)out[O_SRC + ok];
        int  src_j = (int)out[O_SRC + oj];
        bool no_k  = out[O_NOEXT + ok] != 0.0f;
        bool no_j  = out[O_NOEXT + oj] != 0.0f;
        int  lens_k = (int)out[O_LENS + ok];
        int  lens_j = (int)out[O_LENS + oj];
        int  ext_k = no_k ? src_k : (int)out[O_LAST + ok];
        int  ext_j = no_j ? src_j : (int)out[O_LAST + oj];
        int  plen_j = lens_j - (no_j ? 0 : 1);
        bool prefix = pip[((size_t)n*KPP + src_k)*KPP + src_j] != 0;
        bool leq    = lens_k <= lens_j;
        int  tstar  = max(lens_k - 1, 0);
        int  tmj;
        if (tstar == plen_j)   tmj = ext_j;
        else if (tstar < SS)   tmj = yprev[((size_t)tstar*NB + n)*KPP + src_j];
        else                   tmj = 0;
        bool matches = (tmj == ext_k);
        bool res = prefix && leq && (no_k || matches);
        out[O_PREF + (size_t)n*WID*WID + (size_t)k*WID + j] = res ? 1.0f : 0.0f;
    }
}

extern "C" void kernel_launch(void* const* d_in, const int* in_sizes, int n_in,
                              void* d_out, int out_size, void* d_ws, size_t ws_size,
                              hipStream_t stream) {
    const float* ext    = (const float*)d_in[0];
    const float* nonext = (const float*)d_in[1];
    const float* blank  = (const float*)d_in[2];
    const float* nbp    = (const float*)d_in[3];
    const float* bp     = (const float*)d_in[4];
    const int*   yprev  = (const int*)d_in[5];
    const int*   ylast  = (const int*)d_in[6];
    const int*   ylens  = (const int*)d_in[7];
    const int*   pip    = (const int*)d_in[8];
    float* out = (float*)d_out;

    unsigned* wsF  = (unsigned*)d_ws;                      // NB*64*32 u32 (1 MB)
    int*      wsI  = (int*)d_ws + NB*NWAVE*WID;            // +1 MB
    float*    wsAb = (float*)d_ws + 2*NB*NWAVE*WID;        // NB*KPP*KPP floats (512 KB)

    slice_topk_kernel<<<NB*KBLK, 256, 0, stream>>>(ext, nbp, bp, yprev, ylast,
                                                   ylens, pip, wsF, wsI, wsAb);
    merge_kernel<<<NB, 256, 0, stream>>>(nonext, blank, nbp, bp,
                                         ylast, ylens, wsF, wsI, wsAb, out);
    int tot = (int)(SZ_YNEXT + SZ_PREF);
    epilogue_kernel<<<(tot + 255)/256, 256, 0, stream>>>(yprev, pip, out);
}